// Round 1
// baseline (227.214 us; speedup 1.0000x reference)
//
#include <hip/hip_runtime.h>

// Leaky LIF SNN forward:
//   reset_t = H(mem_{t-1} - 1)
//   mem_t   = 0.5*mem_{t-1} + x_t - reset_t
//   spk_t   = H(mem_t - 1)
// x, spk: [T=128, B=64, N=4096] fp32. Neurons independent -> one thread per
// 4 consecutive neurons (float4), sequential loop over T. Coalesced at every t.

#define T_STEPS 128
#define UNROLL 8

__global__ __launch_bounds__(256) void snn_leaky_fwd(const float4* __restrict__ x,
                                                     float4* __restrict__ out,
                                                     int n4) {
    const int idx = blockIdx.x * blockDim.x + threadIdx.x;
    if (idx >= n4) return;

    const float4* xp = x + idx;
    float4* op = out + idx;

    float4 mem = make_float4(0.f, 0.f, 0.f, 0.f);

    for (int t = 0; t < T_STEPS; t += UNROLL) {
        // Issue all UNROLL loads first (independent addresses) so the compiler
        // keeps them in flight together; only 4 waves/CU so ILP does the
        // latency hiding here.
        float4 xt[UNROLL];
#pragma unroll
        for (int u = 0; u < UNROLL; ++u) {
            xt[u] = xp[(size_t)(t + u) * (size_t)n4];
        }
#pragma unroll
        for (int u = 0; u < UNROLL; ++u) {
            const float4 v = xt[u];
            float4 spk;
            // reset uses PREVIOUS mem; strict > matches (v > 0) Heaviside
            mem.x = 0.5f * mem.x + v.x - (mem.x > 1.0f ? 1.0f : 0.0f);
            mem.y = 0.5f * mem.y + v.y - (mem.y > 1.0f ? 1.0f : 0.0f);
            mem.z = 0.5f * mem.z + v.z - (mem.z > 1.0f ? 1.0f : 0.0f);
            mem.w = 0.5f * mem.w + v.w - (mem.w > 1.0f ? 1.0f : 0.0f);
            spk.x = mem.x > 1.0f ? 1.0f : 0.0f;
            spk.y = mem.y > 1.0f ? 1.0f : 0.0f;
            spk.z = mem.z > 1.0f ? 1.0f : 0.0f;
            spk.w = mem.w > 1.0f ? 1.0f : 0.0f;
            op[(size_t)(t + u) * (size_t)n4] = spk;
        }
    }
}

extern "C" void kernel_launch(void* const* d_in, const int* in_sizes, int n_in,
                              void* d_out, int out_size, void* d_ws, size_t ws_size,
                              hipStream_t stream) {
    const float4* x = (const float4*)d_in[0];
    float4* out = (float4*)d_out;

    const int total = in_sizes[0];          // T*B*N = 128*64*4096
    const int nstep = total / T_STEPS;      // B*N   = 262144
    const int n4 = nstep / 4;               // 65536 float4 groups

    const int block = 256;
    const int grid = (n4 + block - 1) / block;   // 256 blocks
    snn_leaky_fwd<<<grid, block, 0, stream>>>(x, out, n4);
}